// Round 1
// baseline (167.000 us; speedup 1.0000x reference)
//
#include <hip/hip_runtime.h>
#include <math.h>

#define PI_F 3.14159265358979323846f
#define SF 0.99999f

// Stockham radix-2 512-point complex FFT in LDS.
// 256 threads, one butterfly per thread per stage, 9 stages.
// sgn = +1.0f : forward DFT (e^{-2pi i nk/N})
// sgn = -1.0f : unnormalized inverse (e^{+2pi i nk/N}); caller scales by 1/512.
// Input in (Are,Aim); output lands in (Bre,Bim) (9 stages = odd ping-pong count).
// Ends with __syncthreads() after the final stage's writes.
__device__ __forceinline__ void fft512(
    float* Are, float* Aim, float* Bre, float* Bim,
    const float* twc, const float* tws, int t, float sgn)
{
    float* sre = Are; float* sim = Aim;
    float* dre = Bre; float* dim = Bim;
#pragma unroll
    for (int stage = 0; stage < 9; ++stage) {
        const int p = 1 << stage;
        const int k = t & (p - 1);
        const float ur = sre[t],       ui = sim[t];
        const float vr = sre[t + 256], vi = sim[t + 256];
        const int twi = k << (8 - stage);
        const float wr = twc[twi];
        const float wi = sgn * tws[twi];
        const float tr = wr * vr - wi * vi;
        const float ti = wr * vi + wi * vr;
        const int jj = ((t - k) << 1) + k;
        dre[jj]     = ur + tr;  dim[jj]     = ui + ti;
        dre[jj + p] = ur - tr;  dim[jj + p] = ui - ti;
        __syncthreads();
        float* tp;
        tp = sre; sre = dre; dre = tp;
        tp = sim; sim = dim; dim = tp;
    }
}

__global__ __launch_bounds__(256, 2) void pbfd_kernel(
    const float* __restrict__ g_mic,   // (B,256)
    const float* __restrict__ g_lsb,   // (B,1280)
    const float* __restrict__ g_phie,  // (B,257)
    const float* __restrict__ g_p1,    // (B,257,4)
    const float* __restrict__ g_hr,    // (B,257,4)
    const float* __restrict__ g_hi,    // (B,257,4)
    float* __restrict__ g_out)         // (B,256)
{
    const int b = blockIdx.x;
    const int t = threadIdx.x;  // 0..255 ; thread t owns bin t, thread 0 also bin 256

    __shared__ float Are[512], Aim[512], Bre[512], Bim[512];
    __shared__ float twc[256], tws[256];

    // twiddle table: tw[i] = exp(-i*pi*i/256)
    {
        float s, c;
        sincosf(-PI_F * (float)t * (1.0f / 256.0f), &s, &c);
        twc[t] = c; tws[t] = s;
    }

    const float micv = g_mic[(size_t)b * 256 + t];

    // per-bin state in registers (bin t; thread 0 also holds bin 256 in *2 regs)
    float hr[4], hi[4], p1v[4];
    {
        const float4 h4r = ((const float4*)g_hr)[(size_t)b * 257 + t];
        const float4 h4i = ((const float4*)g_hi)[(size_t)b * 257 + t];
        const float4 p4  = ((const float4*)g_p1)[(size_t)b * 257 + t];
        hr[0]=h4r.x; hr[1]=h4r.y; hr[2]=h4r.z; hr[3]=h4r.w;
        hi[0]=h4i.x; hi[1]=h4i.y; hi[2]=h4i.z; hi[3]=h4i.w;
        p1v[0]=p4.x; p1v[1]=p4.y; p1v[2]=p4.z; p1v[3]=p4.w;
    }
    float phie = g_phie[(size_t)b * 257 + t];

    float hr2[4]={0,0,0,0}, hi2[4]={0,0,0,0}, p1v2[4]={0,0,0,0};
    float phie2 = 0.f;
    if (t == 0) {
        const float4 h4r = ((const float4*)g_hr)[(size_t)b * 257 + 256];
        const float4 h4i = ((const float4*)g_hi)[(size_t)b * 257 + 256];
        const float4 p4  = ((const float4*)g_p1)[(size_t)b * 257 + 256];
        hr2[0]=h4r.x; hr2[1]=h4r.y; hr2[2]=h4r.z; hr2[3]=h4r.w;
        hi2[0]=h4i.x; hi2[1]=h4i.y; hi2[2]=h4i.z; hi2[3]=h4i.w;
        p1v2[0]=p4.x; p1v2[1]=p4.y; p1v2[2]=p4.z; p1v2[3]=p4.w;
        phie2 = g_phie[(size_t)b * 257 + 256];
    }

    float xr[4], xi[4];
    float x2r[4]={0,0,0,0}, x2i[4]={0,0,0,0};

    const float* lb = g_lsb + (size_t)b * 1280;

    // ---- X[j] = rfft512(frame j), frames overlap by 256 ----
#pragma unroll
    for (int j = 0; j < 4; ++j) {
        Are[t]       = lb[j * 256 + t];
        Are[t + 256] = lb[j * 256 + 256 + t];
        Aim[t] = 0.f; Aim[t + 256] = 0.f;
        __syncthreads();
        fft512(Are, Aim, Bre, Bim, twc, tws, t, 1.0f);
        xr[j] = Bre[t]; xi[j] = Bim[t];               // own bin (stage-8 writer == self)
        if (t == 0) { x2r[j] = Bre[256]; x2i[j] = Bim[256]; }
        __syncthreads();                               // B reads done before next stage-0 B writes
    }

    // ---- fd_fb_hat = sum_j X*H ; est = irfft(.)[256:] ----
    {
        float cr = 0.f, ci = 0.f;
#pragma unroll
        for (int j = 0; j < 4; ++j) {
            cr += xr[j]*hr[j] - xi[j]*hi[j];
            ci += xr[j]*hi[j] + xi[j]*hr[j];
        }
        if (t == 0) {
            float c2r = 0.f;
#pragma unroll
            for (int j = 0; j < 4; ++j) c2r += x2r[j]*hr2[j] - x2i[j]*hi2[j];
            Are[0]   = cr;  Aim[0]   = 0.f;   // irfft ignores DC imag
            Are[256] = c2r; Aim[256] = 0.f;   // irfft ignores Nyquist imag
        } else {
            Are[t] = cr;        Aim[t] = ci;
            Are[512 - t] = cr;  Aim[512 - t] = -ci;
        }
        __syncthreads();
        fft512(Are, Aim, Bre, Bim, twc, tws, t, -1.0f);   // unscaled inverse
    }

    // ---- d = mic - est ; E = rfft512([0(256); d]) (fd_mic - fd_est_fb fused) ----
    {
        const float est = Bre[t + 256] * (1.0f / 512.0f); // own bin
        const float d = micv - est;
        Are[t] = 0.f;       Aim[t] = 0.f;
        Are[t + 256] = d;   Aim[t + 256] = 0.f;
        __syncthreads();
        fft512(Are, Aim, Bre, Bim, twc, tws, t, 1.0f);
    }

    // ---- E, updated phi_e ----
    float er = Bre[t], ei = Bim[t];
    float pe = 0.7f * phie + 0.3f * (er*er + ei*ei);
    float e2r_ = 0.f, e2i_ = 0.f, pe2 = 0.f;
    if (t == 0) {
        e2r_ = Bre[256]; e2i_ = Bim[256];
        pe2 = 0.7f * phie2 + 0.3f * (e2r_*e2r_ + e2i_*e2i_);
    }
    __syncthreads();

    // ---- per-partition: KE -> irfft -> mask -> rfft -> H_new ----
#pragma unroll
    for (int j = 0; j < 4; ++j) {
        {
            const float xx = xr[j]*xr[j] + xi[j]*xi[j];
            const float R  = xx * p1v[j] + 2.0f * pe + 1e-10f;
            const float inv = 1.0f / R;
            const float kr =  p1v[j] * xr[j] * inv;
            const float ki = -p1v[j] * xi[j] * inv;
            const float ker = kr*er - ki*ei;
            const float kei = kr*ei + ki*er;
            if (t == 0) {
                const float xx2 = x2r[j]*x2r[j] + x2i[j]*x2i[j];
                const float R2  = xx2 * p1v2[j] + 2.0f * pe2 + 1e-10f;
                const float inv2 = 1.0f / R2;
                const float kr2 =  p1v2[j] * x2r[j] * inv2;
                const float ki2 = -p1v2[j] * x2i[j] * inv2;
                const float ker2 = kr2*e2r_ - ki2*e2i_;
                Are[0]   = ker;  Aim[0]   = 0.f;
                Are[256] = ker2; Aim[256] = 0.f;
            } else {
                Are[t] = ker;        Aim[t] = kei;
                Are[512 - t] = ker;  Aim[512 - t] = -kei;
            }
        }
        __syncthreads();
        fft512(Are, Aim, Bre, Bim, twc, tws, t, -1.0f);   // dH (unscaled)
        // mask t<256, scale 1/512, rebuild forward-FFT input
        Are[t]       = Bre[t] * (1.0f / 512.0f);           // own bin
        Are[t + 256] = 0.f;
        Aim[t] = 0.f; Aim[t + 256] = 0.f;
        __syncthreads();
        fft512(Are, Aim, Bre, Bim, twc, tws, t, 1.0f);     // fd_dH
        hr[j] = SF * (hr[j] + Bre[t]);
        hi[j] = SF * (hi[j] + Bim[t]);
        if (t == 0) {
            hr2[j] = SF * (hr2[j] + Bre[256]);
            hi2[j] = SF * (hi2[j] + Bim[256]);
        }
        __syncthreads();
    }

    // ---- fd_fb_hat2 with H_new ; enhanced = mic - irfft(.)[256:] ----
    {
        float cr = 0.f, ci = 0.f;
#pragma unroll
        for (int j = 0; j < 4; ++j) {
            cr += xr[j]*hr[j] - xi[j]*hi[j];
            ci += xr[j]*hi[j] + xi[j]*hr[j];
        }
        if (t == 0) {
            float c2r = 0.f;
#pragma unroll
            for (int j = 0; j < 4; ++j) c2r += x2r[j]*hr2[j] - x2i[j]*hi2[j];
            Are[0]   = cr;  Aim[0]   = 0.f;
            Are[256] = c2r; Aim[256] = 0.f;
        } else {
            Are[t] = cr;        Aim[t] = ci;
            Are[512 - t] = cr;  Aim[512 - t] = -ci;
        }
        __syncthreads();
        fft512(Are, Aim, Bre, Bim, twc, tws, t, -1.0f);
        g_out[(size_t)b * 256 + t] = micv - Bre[t + 256] * (1.0f / 512.0f);
    }
}

extern "C" void kernel_launch(void* const* d_in, const int* in_sizes, int n_in,
                              void* d_out, int out_size, void* d_ws, size_t ws_size,
                              hipStream_t stream) {
    const float* mic  = (const float*)d_in[0];
    const float* lsb  = (const float*)d_in[1];
    const float* phie = (const float*)d_in[2];
    // d_in[3] = phi_f: not needed for the 'enhanced' output
    const float* p1   = (const float*)d_in[4];
    const float* hr   = (const float*)d_in[5];
    const float* hi   = (const float*)d_in[6];
    float* out = (float*)d_out;

    const int B = in_sizes[0] / 256;  // N_MIC == 1
    pbfd_kernel<<<B, 256, 0, stream>>>(mic, lsb, phie, p1, hr, hi, out);
}

// Round 2
// 80.270 us; speedup vs baseline: 2.0805x; 2.0805x over previous
//
#include <hip/hip_runtime.h>
#include <math.h>

#define SF 0.99999f
#define PI2 6.283185307179586476925f
#define SWZ(c) ((c) ^ (((c) >> 4) & 15))
// compiler-only fence: keeps LDS read/write phases ordered (cross-lane data
// exchange within a wave; HW LDS pipe is in-order per wave, this stops the
// compiler from hoisting provably-"independent" per-thread accesses).
#define LDSFENCE() asm volatile("" ::: "memory")

// u *= exp(SGN * i * theta), given c = cos(theta), s = sin(theta)
template<int SGN>
__device__ __forceinline__ void twmul(float& ur, float& ui, float c, float s) {
    const float ss = (SGN < 0) ? -s : s;
    const float r = ur * c - ui * ss;
    const float i = ui * c + ur * ss;
    ur = r; ui = i;
}

// 8-point DFT across registers. SGN=-1: forward (e^{-2pi i/8}); SGN=+1: inverse.
template<int SGN>
__device__ __forceinline__ void bfly8(float* ur, float* ui) {
    const float C2 = 0.70710678118654752440f;
    float ar[4], ai[4], br[4], bi[4];
#pragma unroll
    for (int m = 0; m < 4; ++m) {
        ar[m] = ur[m] + ur[m + 4]; ai[m] = ui[m] + ui[m + 4];
        br[m] = ur[m] - ur[m + 4]; bi[m] = ui[m] - ui[m + 4];
    }
    float b1r, b1i, b2r, b2i, b3r, b3i;
    if (SGN < 0) {
        b1r = C2 * (br[1] + bi[1]); b1i = C2 * (bi[1] - br[1]);
        b2r = bi[2];                b2i = -br[2];
        b3r = C2 * (bi[3] - br[3]); b3i = -C2 * (br[3] + bi[3]);
    } else {
        b1r = C2 * (br[1] - bi[1]); b1i = C2 * (bi[1] + br[1]);
        b2r = -bi[2];               b2i = br[2];
        b3r = -C2 * (br[3] + bi[3]); b3i = C2 * (br[3] - bi[3]);
    }
    // even outputs: DFT4 of a
    const float e0r = ar[0] + ar[2], e0i = ai[0] + ai[2];
    const float e1r = ar[0] - ar[2], e1i = ai[0] - ai[2];
    const float o0r = ar[1] + ar[3], o0i = ai[1] + ai[3];
    const float o1r = ar[1] - ar[3], o1i = ai[1] - ai[3];
    ur[0] = e0r + o0r; ui[0] = e0i + o0i;
    ur[4] = e0r - o0r; ui[4] = e0i - o0i;
    if (SGN < 0) { ur[2] = e1r + o1i; ui[2] = e1i - o1r; ur[6] = e1r - o1i; ui[6] = e1i + o1r; }
    else         { ur[2] = e1r - o1i; ui[2] = e1i + o1r; ur[6] = e1r + o1i; ui[6] = e1i - o1r; }
    // odd outputs: DFT4 of (b0, b1, b2, b3)
    const float f0r = br[0] + b2r, f0i = bi[0] + b2i;
    const float f1r = br[0] - b2r, f1i = bi[0] - b2i;
    const float g0r = b1r + b3r, g0i = b1i + b3i;
    const float g1r = b1r - b3r, g1i = b1i - b3i;
    ur[1] = f0r + g0r; ui[1] = f0i + g0i;
    ur[5] = f0r - g0r; ui[5] = f0i - g0i;
    if (SGN < 0) { ur[3] = f1r + g1i; ui[3] = f1i - g1r; ur[7] = f1r - g1i; ui[7] = f1i + g1r; }
    else         { ur[3] = f1r - g1i; ui[3] = f1i + g1r; ur[7] = f1r + g1i; ui[7] = f1i - g1r; }
}

// Wave-local 512-pt complex FFT, Stockham radix-8, 3 stages.
// In/out: ur/ui[m] = element (t + 64*m); natural order both sides.
// Zero barriers: exchanges via this wave's private LDS buffers.
template<int SGN>
__device__ __forceinline__ void fft512w(float* ur, float* ui,
                                        float2* __restrict__ bufA,
                                        float2* __restrict__ bufB,
                                        const float2* __restrict__ tw2,
                                        const float2* __restrict__ tw3,
                                        int t) {
    // stage 1: p=1, k=0, no twiddle
    bfly8<SGN>(ur, ui);
    LDSFENCE();
#pragma unroll
    for (int m = 0; m < 8; ++m) bufA[SWZ(8 * t + m)] = make_float2(ur[m], ui[m]);
    LDSFENCE();
#pragma unroll
    for (int m = 0; m < 8; ++m) { const float2 v = bufA[SWZ(t + 64 * m)]; ur[m] = v.x; ui[m] = v.y; }
    // stage 2: p=8, k=t&7, twiddle W64^{m k}
    const int k2 = t & 7;
#pragma unroll
    for (int m = 1; m < 8; ++m) { const float2 w = tw2[m * 8 + k2]; twmul<SGN>(ur[m], ui[m], w.x, w.y); }
    bfly8<SGN>(ur, ui);
    const int jj = ((t >> 3) << 6) + k2;
    LDSFENCE();
#pragma unroll
    for (int m = 0; m < 8; ++m) bufB[SWZ(jj + 8 * m)] = make_float2(ur[m], ui[m]);
    LDSFENCE();
#pragma unroll
    for (int m = 0; m < 8; ++m) { const float2 v = bufB[SWZ(t + 64 * m)]; ur[m] = v.x; ui[m] = v.y; }
    // stage 3: p=64, k=t, twiddle W512^{m t}
#pragma unroll
    for (int m = 1; m < 8; ++m) { const float2 w = tw3[m * 64 + t]; twmul<SGN>(ur[m], ui[m], w.x, w.y); }
    bfly8<SGN>(ur, ui);
    LDSFENCE();
}

__global__ __launch_bounds__(256) void pbfd_kernel(
    const float* __restrict__ g_mic,   // (B,256)
    const float* __restrict__ g_lsb,   // (B,1280)
    const float* __restrict__ g_phie,  // (B,257)
    const float* __restrict__ g_p1,    // (B,257,4)
    const float* __restrict__ g_hr,    // (B,257,4)
    const float* __restrict__ g_hi,    // (B,257,4)
    float* __restrict__ g_out,         // (B,256)
    int B) {
    __shared__ float2 tw2[64];          // [m][k], theta = 2pi m k / 64
    __shared__ float2 tw3[512];         // [m][t], theta = 2pi m t / 512
    __shared__ float2 xch[4][2][512];   // per-wave ping/pong exchange buffers

    const int tid = threadIdx.x;
    for (int e = tid; e < 512; e += 256) {
        const int m = e >> 6, tt = e & 63;
        float s, c;
        sincosf(PI2 * (float)(m * tt) * (1.0f / 512.0f), &s, &c);
        tw3[e] = make_float2(c, s);
    }
    if (tid < 64) {
        const int m = tid >> 3, k = tid & 7;
        float s, c;
        sincosf(PI2 * (float)(m * k) * (1.0f / 64.0f), &s, &c);
        tw2[tid] = make_float2(c, s);
    }
    __syncthreads();  // the only barrier

    const int w = tid >> 6;
    const int t = tid & 63;
    const int elem = blockIdx.x * 4 + w;
    if (elem >= B) return;

    float2* bufA = &xch[w][0][0];
    float2* bufB = &xch[w][1][0];

    // ---- X[j] = FFT512(frame j), full 512-bin spectra in registers ----
    float xr[4][8], xi[4][8];
    {
        const float* lb = g_lsb + (size_t)elem * 1280;
#pragma unroll
        for (int j = 0; j < 4; ++j) {
            float ur[8], ui[8];
#pragma unroll
            for (int m = 0; m < 8; ++m) { ur[m] = lb[j * 256 + t + 64 * m]; ui[m] = 0.f; }
            fft512w<-1>(ur, ui, bufA, bufB, tw2, tw3, t);
#pragma unroll
            for (int m = 0; m < 8; ++m) { xr[j][m] = ur[m]; xi[j][m] = ui[m]; }
        }
    }

    // ---- H: bins t+64m; m>=4 are conj mirrors of bin 512-(t+64m) ----
    float hr[4][8], hi[4][8];
    {
        const float4* hr4 = (const float4*)g_hr + (size_t)elem * 257;
        const float4* hi4 = (const float4*)g_hi + (size_t)elem * 257;
#pragma unroll
        for (int m = 0; m < 4; ++m) {
            const float4 a = hr4[t + 64 * m], b = hi4[t + 64 * m];
            hr[0][m] = a.x; hr[1][m] = a.y; hr[2][m] = a.z; hr[3][m] = a.w;
            hi[0][m] = b.x; hi[1][m] = b.y; hi[2][m] = b.z; hi[3][m] = b.w;
        }
#pragma unroll
        for (int m = 4; m < 8; ++m) {
            const int bm = 512 - (t + 64 * m);  // in [1,256]
            const float4 a = hr4[bm], b = hi4[bm];
            hr[0][m] = a.x; hr[1][m] = a.y; hr[2][m] = a.z; hr[3][m] = a.w;
            hi[0][m] = -b.x; hi[1][m] = -b.y; hi[2][m] = -b.z; hi[3][m] = -b.w;
        }
    }

    float mv[4];
    {
        const float* micp = g_mic + (size_t)elem * 256;
#pragma unroll
        for (int q = 0; q < 4; ++q) mv[q] = micp[t + 64 * q];
    }

    float ur[8], ui[8];

    // ---- est = Re(IFFT(sum_j X*H))[256:], d = mic - est ----
#pragma unroll
    for (int m = 0; m < 8; ++m) {
        float cr = 0.f, ci = 0.f;
#pragma unroll
        for (int j = 0; j < 4; ++j) {
            cr += xr[j][m] * hr[j][m] - xi[j][m] * hi[j][m];
            ci += xr[j][m] * hi[j][m] + xi[j][m] * hr[j][m];
        }
        ur[m] = cr; ui[m] = ci;
    }
    fft512w<1>(ur, ui, bufA, bufB, tw2, tw3, t);
    float d4[4];
#pragma unroll
    for (int q = 0; q < 4; ++q) d4[q] = mv[q] - ur[4 + q] * (1.0f / 512.0f);

    // ---- E = FFT512([zeros(256); d]) : input is lane-local ----
#pragma unroll
    for (int m = 0; m < 4; ++m) { ur[m] = 0.f; ui[m] = 0.f; }
#pragma unroll
    for (int q = 0; q < 4; ++q) { ur[4 + q] = d4[q]; ui[4 + q] = 0.f; }
    fft512w<-1>(ur, ui, bufA, bufB, tw2, tw3, t);
    float er[8], ei[8];
#pragma unroll
    for (int m = 0; m < 8; ++m) { er[m] = ur[m]; ei[m] = ui[m]; }

    // ---- phi_e update (even-symmetric full spectrum) ----
    float pe[8];
    {
        const float* php = g_phie + (size_t)elem * 257;
#pragma unroll
        for (int m = 0; m < 8; ++m) {
            const int bm = (m < 4) ? (t + 64 * m) : (512 - (t + 64 * m));
            pe[m] = 0.7f * php[bm] + 0.3f * (er[m] * er[m] + ei[m] * ei[m]);
        }
    }

    // ---- per-partition: K*E -> IFFT -> mask -> FFT -> H update ----
    {
        const float* p1p = g_p1 + (size_t)elem * 257 * 4;
#pragma unroll
        for (int j = 0; j < 4; ++j) {
#pragma unroll
            for (int m = 0; m < 8; ++m) {
                const int bm = (m < 4) ? (t + 64 * m) : (512 - (t + 64 * m));
                const float p1 = p1p[bm * 4 + j];
                const float xx = xr[j][m] * xr[j][m] + xi[j][m] * xi[j][m];
                const float R = xx * p1 + 2.f * pe[m] + 1e-10f;
                const float inv = 1.f / R;
                const float kr = p1 * xr[j][m] * inv;
                const float ki = -p1 * xi[j][m] * inv;
                ur[m] = kr * er[m] - ki * ei[m];
                ui[m] = kr * ei[m] + ki * er[m];
            }
            fft512w<1>(ur, ui, bufA, bufB, tw2, tw3, t);  // dH (unscaled)
#pragma unroll
            for (int m = 0; m < 4; ++m) { ur[m] *= (1.0f / 512.0f); ui[m] = 0.f; }
#pragma unroll
            for (int m = 4; m < 8; ++m) { ur[m] = 0.f; ui[m] = 0.f; }
            fft512w<-1>(ur, ui, bufA, bufB, tw2, tw3, t);  // fd_dH
#pragma unroll
            for (int m = 0; m < 8; ++m) {
                hr[j][m] = SF * (hr[j][m] + ur[m]);
                hi[j][m] = SF * (hi[j][m] + ui[m]);
            }
        }
    }

    // ---- enhanced = mic - Re(IFFT(sum_j X*H_new))[256:] ----
#pragma unroll
    for (int m = 0; m < 8; ++m) {
        float cr = 0.f, ci = 0.f;
#pragma unroll
        for (int j = 0; j < 4; ++j) {
            cr += xr[j][m] * hr[j][m] - xi[j][m] * hi[j][m];
            ci += xr[j][m] * hi[j][m] + xi[j][m] * hr[j][m];
        }
        ur[m] = cr; ui[m] = ci;
    }
    fft512w<1>(ur, ui, bufA, bufB, tw2, tw3, t);
    {
        float* op = g_out + (size_t)elem * 256;
#pragma unroll
        for (int q = 0; q < 4; ++q) op[t + 64 * q] = mv[q] - ur[4 + q] * (1.0f / 512.0f);
    }
}

extern "C" void kernel_launch(void* const* d_in, const int* in_sizes, int n_in,
                              void* d_out, int out_size, void* d_ws, size_t ws_size,
                              hipStream_t stream) {
    const float* mic  = (const float*)d_in[0];
    const float* lsb  = (const float*)d_in[1];
    const float* phie = (const float*)d_in[2];
    // d_in[3] = phi_f: dead for the 'enhanced' output
    const float* p1   = (const float*)d_in[4];
    const float* hr   = (const float*)d_in[5];
    const float* hi   = (const float*)d_in[6];
    float* out = (float*)d_out;

    const int B = in_sizes[0] / 256;  // N_MIC == 1
    const int blocks = (B + 3) / 4;   // 4 elements (waves) per 256-thread block
    pbfd_kernel<<<blocks, 256, 0, stream>>>(mic, lsb, phie, p1, hr, hi, out, B);
}

// Round 3
// 55.663 us; speedup vs baseline: 3.0002x; 1.4421x over previous
//
#include <hip/hip_runtime.h>
#include <math.h>

#define SF 0.99999f
#define PI2 6.283185307179586476925f
#define SWZ(c) ((c) ^ (((c) >> 4) & 15))
// compiler-only fence: orders same-wave LDS write/read phases (HW LDS pipe is
// in-order per wave; this stops compiler reordering).
#define LDSFENCE() asm volatile("" ::: "memory")

template<int SGN>
__device__ __forceinline__ void twmul(float& ur, float& ui, float c, float s) {
    const float ss = (SGN < 0) ? -s : s;
    const float r = ur * c - ui * ss;
    const float i = ui * c + ur * ss;
    ur = r; ui = i;
}

// 8-point DFT across registers. SGN=-1: forward; SGN=+1: inverse.
template<int SGN>
__device__ __forceinline__ void bfly8(float* ur, float* ui) {
    const float C2 = 0.70710678118654752440f;
    float ar[4], ai[4], br[4], bi[4];
#pragma unroll
    for (int m = 0; m < 4; ++m) {
        ar[m] = ur[m] + ur[m + 4]; ai[m] = ui[m] + ui[m + 4];
        br[m] = ur[m] - ur[m + 4]; bi[m] = ui[m] - ui[m + 4];
    }
    float b1r, b1i, b2r, b2i, b3r, b3i;
    if (SGN < 0) {
        b1r = C2 * (br[1] + bi[1]); b1i = C2 * (bi[1] - br[1]);
        b2r = bi[2];                b2i = -br[2];
        b3r = C2 * (bi[3] - br[3]); b3i = -C2 * (br[3] + bi[3]);
    } else {
        b1r = C2 * (br[1] - bi[1]); b1i = C2 * (bi[1] + br[1]);
        b2r = -bi[2];               b2i = br[2];
        b3r = -C2 * (br[3] + bi[3]); b3i = C2 * (br[3] - bi[3]);
    }
    const float e0r = ar[0] + ar[2], e0i = ai[0] + ai[2];
    const float e1r = ar[0] - ar[2], e1i = ai[0] - ai[2];
    const float o0r = ar[1] + ar[3], o0i = ai[1] + ai[3];
    const float o1r = ar[1] - ar[3], o1i = ai[1] - ai[3];
    ur[0] = e0r + o0r; ui[0] = e0i + o0i;
    ur[4] = e0r - o0r; ui[4] = e0i - o0i;
    if (SGN < 0) { ur[2] = e1r + o1i; ui[2] = e1i - o1r; ur[6] = e1r - o1i; ui[6] = e1i + o1r; }
    else         { ur[2] = e1r - o1i; ui[2] = e1i + o1r; ur[6] = e1r + o1i; ui[6] = e1i - o1r; }
    const float f0r = br[0] + b2r, f0i = bi[0] + b2i;
    const float f1r = br[0] - b2r, f1i = bi[0] - b2i;
    const float g0r = b1r + b3r, g0i = b1i + b3i;
    const float g1r = b1r - b3r, g1i = b1i - b3i;
    ur[1] = f0r + g0r; ui[1] = f0i + g0i;
    ur[5] = f0r - g0r; ui[5] = f0i - g0i;
    if (SGN < 0) { ur[3] = f1r + g1i; ui[3] = f1i - g1r; ur[7] = f1r - g1i; ui[7] = f1i + g1r; }
    else         { ur[3] = f1r - g1i; ui[3] = f1i + g1r; ur[7] = f1r + g1i; ui[7] = f1i - g1r; }
}

// Wave-local 512-pt complex FFT, Stockham radix-8, 3 stages, single LDS buffer.
// slot m of lane t <-> element (t + 64*m), natural order both sides. No barriers.
template<int SGN>
__device__ __forceinline__ void fft512w(float* ur, float* ui,
                                        float2* __restrict__ buf,
                                        const float2* __restrict__ tw2,
                                        const float2* __restrict__ tw3,
                                        int t) {
    bfly8<SGN>(ur, ui);
    LDSFENCE();
#pragma unroll
    for (int m = 0; m < 8; ++m) buf[SWZ(8 * t + m)] = make_float2(ur[m], ui[m]);
    LDSFENCE();
#pragma unroll
    for (int m = 0; m < 8; ++m) { const float2 v = buf[SWZ(t + 64 * m)]; ur[m] = v.x; ui[m] = v.y; }
    const int k2 = t & 7;
#pragma unroll
    for (int m = 1; m < 8; ++m) { const float2 w = tw2[m * 8 + k2]; twmul<SGN>(ur[m], ui[m], w.x, w.y); }
    bfly8<SGN>(ur, ui);
    const int jj = ((t >> 3) << 6) + k2;
    LDSFENCE();
#pragma unroll
    for (int m = 0; m < 8; ++m) buf[SWZ(jj + 8 * m)] = make_float2(ur[m], ui[m]);
    LDSFENCE();
#pragma unroll
    for (int m = 0; m < 8; ++m) { const float2 v = buf[SWZ(t + 64 * m)]; ur[m] = v.x; ui[m] = v.y; }
#pragma unroll
    for (int m = 1; m < 8; ++m) { const float2 w = tw3[m * 64 + t]; twmul<SGN>(ur[m], ui[m], w.x, w.y); }
    bfly8<SGN>(ur, ui);
    LDSFENCE();
}

__global__ __launch_bounds__(256, 3) void pbfd_kernel(
    const float* __restrict__ g_mic,   // (B,256)
    const float* __restrict__ g_lsb,   // (B,1280)
    const float* __restrict__ g_phie,  // (B,257)
    const float* __restrict__ g_p1,    // (B,257,4)
    const float* __restrict__ g_hr,    // (B,257,4)
    const float* __restrict__ g_hi,    // (B,257,4)
    float* __restrict__ g_out,         // (B,256)
    int B) {
    __shared__ float2 tw2[64];
    __shared__ float2 tw3[512];
    __shared__ float2 xch[4][512];     // one exchange buffer per wave

    const int tid = threadIdx.x;
    for (int e = tid; e < 512; e += 256) {
        const int m = e >> 6, tt = e & 63;
        float s, c;
        sincosf(PI2 * (float)(m * tt) * (1.0f / 512.0f), &s, &c);
        tw3[e] = make_float2(c, s);
    }
    if (tid < 64) {
        const int m = tid >> 3, k = tid & 7;
        float s, c;
        sincosf(PI2 * (float)(m * k) * (1.0f / 64.0f), &s, &c);
        tw2[tid] = make_float2(c, s);
    }
    __syncthreads();  // the only barrier

    const int w = tid >> 6;
    const int t = tid & 63;
    const int elem = blockIdx.x * 4 + w;
    if (elem >= B) return;
    float2* buf = &xch[w][0];
    const int ml = (64 - t) & 63;  // mirror lane: bin 512-k lives at (ml, 7-m) for t>=1

    float mv[4];
    {
        const float* mp = g_mic + (size_t)elem * 256;
#pragma unroll
        for (int q = 0; q < 4; ++q) mv[q] = mp[t + 64 * q];
    }

    // ---- X: 4 real frame-FFTs as 2 paired complex FFTs; keep low bins + lane0 Nyquist ----
    float xr[4][4], xi[4][4], xn[4];
    {
        const float* lb = g_lsb + (size_t)elem * 1280;
#pragma unroll
        for (int pr = 0; pr < 2; ++pr) {
            float ur[8], ui[8];
#pragma unroll
            for (int m = 0; m < 8; ++m) {
                ur[m] = lb[(2 * pr) * 256 + t + 64 * m];
                ui[m] = lb[(2 * pr + 1) * 256 + t + 64 * m];
            }
            fft512w<-1>(ur, ui, buf, tw2, tw3, t);
#pragma unroll
            for (int m = 0; m < 4; ++m) {
                float zmr = __shfl(ur[7 - m], ml);
                float zmi = __shfl(ui[7 - m], ml);
                if (t == 0) {  // lane0: mirror of bin 64m is slot 8-m (self for m=0)
                    zmr = (m == 0) ? ur[0] : ur[8 - m];
                    zmi = (m == 0) ? ui[0] : ui[8 - m];
                }
                xr[2 * pr][m]     = 0.5f * (ur[m] + zmr);
                xi[2 * pr][m]     = 0.5f * (ui[m] - zmi);
                xr[2 * pr + 1][m] = 0.5f * (ui[m] + zmi);
                xi[2 * pr + 1][m] = -0.5f * (ur[m] - zmr);
            }
            if (t == 0) { xn[2 * pr] = ur[4]; xn[2 * pr + 1] = ui[4]; }  // X[256] real / imag-packed
        }
    }

    // ---- H (low bins; lane0: real part of H[256] — its imag is dead for the output) ----
    float hr_[4][4], hi_[4][4], hn[4];
    float p1s[4][4];  // [m][j]
    {
        const float4* hr4 = (const float4*)g_hr + (size_t)elem * 257;
        const float4* hi4 = (const float4*)g_hi + (size_t)elem * 257;
        const float4* p14 = (const float4*)g_p1 + (size_t)elem * 257;
#pragma unroll
        for (int m = 0; m < 4; ++m) {
            const float4 a = hr4[t + 64 * m], b = hi4[t + 64 * m], p = p14[t + 64 * m];
            hr_[0][m] = a.x; hr_[1][m] = a.y; hr_[2][m] = a.z; hr_[3][m] = a.w;
            hi_[0][m] = b.x; hi_[1][m] = b.y; hi_[2][m] = b.z; hi_[3][m] = b.w;
            p1s[m][0] = p.x; p1s[m][1] = p.y; p1s[m][2] = p.z; p1s[m][3] = p.w;
        }
    }
    float pn[4] = {0, 0, 0, 0};
    if (t == 0) {
        const float4* hr4 = (const float4*)g_hr + (size_t)elem * 257;
        const float4* p14 = (const float4*)g_p1 + (size_t)elem * 257;
        const float4 a = hr4[256], p = p14[256];
        hn[0] = a.x; hn[1] = a.y; hn[2] = a.z; hn[3] = a.w;
        pn[0] = p.x; pn[1] = p.y; pn[2] = p.z; pn[3] = p.w;
    }

    // C = sum_j X*H at low slots; Hermitian high-half reconstruction; IFFT; o4 = Re(out)[4..7]/512
    auto sum_ifft = [&](float o4[4]) {
        float ur[8], ui[8];
#pragma unroll
        for (int m = 0; m < 4; ++m) {
            float cr = 0.f, ci = 0.f;
#pragma unroll
            for (int j = 0; j < 4; ++j) {
                cr += xr[j][m] * hr_[j][m] - xi[j][m] * hi_[j][m];
                ci += xr[j][m] * hi_[j][m] + xi[j][m] * hr_[j][m];
            }
            ur[m] = cr; ui[m] = ci;
        }
#pragma unroll
        for (int m = 4; m < 8; ++m) {  // high slot = conj(mirror-lane low slot 7-m)
            const float cr = __shfl(ur[7 - m], ml);
            const float ci = __shfl(ui[7 - m], ml);
            ur[m] = cr; ui[m] = -ci;
        }
        if (t == 0) {
            ur[5] = ur[3]; ui[5] = -ui[3];
            ur[6] = ur[2]; ui[6] = -ui[2];
            ur[7] = ur[1]; ui[7] = -ui[1];
            float cn = 0.f;
#pragma unroll
            for (int j = 0; j < 4; ++j) cn += xn[j] * hn[j];
            ur[4] = cn; ui[4] = 0.f;  // Nyquist: real
        }
        fft512w<1>(ur, ui, buf, tw2, tw3, t);
#pragma unroll
        for (int q = 0; q < 4; ++q) o4[q] = ur[4 + q] * (1.0f / 512.0f);
    };

    // ---- est (H prior), d = mic - est ----
    float d4[4];
    {
        float o4[4];
        sum_ifft(o4);
#pragma unroll
        for (int q = 0; q < 4; ++q) d4[q] = mv[q] - o4[q];
    }

    // ---- E = FFT([zeros(256); d]) ----
    float er[4], ei[4], en = 0.f;
    {
        float ur[8], ui[8];
#pragma unroll
        for (int m = 0; m < 4; ++m) { ur[m] = 0.f; ui[m] = 0.f; }
#pragma unroll
        for (int q = 0; q < 4; ++q) { ur[4 + q] = d4[q]; ui[4 + q] = 0.f; }
        fft512w<-1>(ur, ui, buf, tw2, tw3, t);
#pragma unroll
        for (int m = 0; m < 4; ++m) { er[m] = ur[m]; ei[m] = ui[m]; }
        if (t == 0) en = ur[4];
    }

    // ---- phi_e ----
    float pe[4], pen = 0.f;
    {
        const float* php = g_phie + (size_t)elem * 257;
#pragma unroll
        for (int m = 0; m < 4; ++m)
            pe[m] = 0.7f * php[t + 64 * m] + 0.3f * (er[m] * er[m] + ei[m] * ei[m]);
        if (t == 0) pen = 0.7f * php[256] + 0.3f * en * en;
    }

    // ---- gradient: partitions paired (0,1), (2,3): IFFT(KE0 + i*KE1) -> mask -> FFT -> unpack ----
#pragma unroll
    for (int pr = 0; pr < 2; ++pr) {
        const int j0 = 2 * pr, j1 = 2 * pr + 1;
        float ur[8], ui[8], gr[4], gi[4];
#pragma unroll
        for (int m = 0; m < 4; ++m) {
            // KE_j = P1_j * conj(X_j) / R_j * E
            const float pa = p1s[m][j0], pb = p1s[m][j1];
            const float xxa = xr[j0][m] * xr[j0][m] + xi[j0][m] * xi[j0][m];
            const float Ra = xxa * pa + 2.f * pe[m] + 1e-10f;
            const float ia = 1.f / Ra;
            const float kra = pa * xr[j0][m] * ia, kia = -pa * xi[j0][m] * ia;
            const float a_r = kra * er[m] - kia * ei[m];
            const float a_i = kra * ei[m] + kia * er[m];
            const float xxb = xr[j1][m] * xr[j1][m] + xi[j1][m] * xi[j1][m];
            const float Rb = xxb * pb + 2.f * pe[m] + 1e-10f;
            const float ib = 1.f / Rb;
            const float krb = pb * xr[j1][m] * ib, kib = -pb * xi[j1][m] * ib;
            const float b_r = krb * er[m] - kib * ei[m];
            const float b_i = krb * ei[m] + kib * er[m];
            ur[m] = a_r - b_i;  ui[m] = a_i + b_r;   // KE0 + i*KE1
            gr[m] = a_r + b_i;  gi[m] = b_r - a_i;   // conj(KE0) + i*conj(KE1) (export for mirror)
        }
#pragma unroll
        for (int m = 4; m < 8; ++m) {
            ur[m] = __shfl(gr[7 - m], ml);
            ui[m] = __shfl(gi[7 - m], ml);
        }
        if (t == 0) {
            ur[5] = gr[3]; ui[5] = gi[3];
            ur[6] = gr[2]; ui[6] = gi[2];
            ur[7] = gr[1]; ui[7] = gi[1];
            const float Rn0 = xn[j0] * xn[j0] * pn[j0] + 2.f * pen + 1e-10f;
            const float Rn1 = xn[j1] * xn[j1] * pn[j1] + 2.f * pen + 1e-10f;
            ur[4] = pn[j0] * xn[j0] / Rn0 * en;   // KE0[256] (real)
            ui[4] = pn[j1] * xn[j1] / Rn1 * en;   // KE1[256] (real)
        }
        fft512w<1>(ur, ui, buf, tw2, tw3, t);  // -> 512*(dH0 + i*dH1), natural order
        // mask n<256 (slots m<4), scale 1/512, FFT the still-packed pair
#pragma unroll
        for (int m = 0; m < 4; ++m) { ur[m] *= (1.0f / 512.0f); ui[m] *= (1.0f / 512.0f); }
#pragma unroll
        for (int m = 4; m < 8; ++m) { ur[m] = 0.f; ui[m] = 0.f; }
        fft512w<-1>(ur, ui, buf, tw2, tw3, t);  // Z = fd_dH0 + i*fd_dH1
        // unpack at low slots: fd0 = (Z + conj(Zm))/2, fd1 = -i/2 (Z - conj(Zm))
#pragma unroll
        for (int m = 0; m < 4; ++m) {
            float zmr = __shfl(ur[7 - m], ml);
            float zmi = __shfl(ui[7 - m], ml);
            if (t == 0) {
                zmr = (m == 0) ? ur[0] : ur[8 - m];
                zmi = (m == 0) ? ui[0] : ui[8 - m];
            }
            const float f0r = 0.5f * (ur[m] + zmr), f0i = 0.5f * (ui[m] - zmi);
            const float f1r = 0.5f * (ui[m] + zmi), f1i = -0.5f * (ur[m] - zmr);
            hr_[j0][m] = SF * (hr_[j0][m] + f0r);
            hi_[j0][m] = SF * (hi_[j0][m] + f0i);
            hr_[j1][m] = SF * (hr_[j1][m] + f1r);
            hi_[j1][m] = SF * (hi_[j1][m] + f1i);
        }
        if (t == 0) {
            hn[j0] = SF * (hn[j0] + ur[4]);  // fd_dH0[256] = Re(Z4)
            hn[j1] = SF * (hn[j1] + ui[4]);  // fd_dH1[256] = Im(Z4)
        }
    }

    // ---- enhanced = mic - Re(IFFT(sum X*H_new))[256:] ----
    {
        float o4[4];
        sum_ifft(o4);
        float* op = g_out + (size_t)elem * 256;
#pragma unroll
        for (int q = 0; q < 4; ++q) op[t + 64 * q] = mv[q] - o4[q];
    }
}

extern "C" void kernel_launch(void* const* d_in, const int* in_sizes, int n_in,
                              void* d_out, int out_size, void* d_ws, size_t ws_size,
                              hipStream_t stream) {
    const float* mic  = (const float*)d_in[0];
    const float* lsb  = (const float*)d_in[1];
    const float* phie = (const float*)d_in[2];
    // d_in[3] = phi_f: dead for the 'enhanced' output
    const float* p1   = (const float*)d_in[4];
    const float* hr   = (const float*)d_in[5];
    const float* hi   = (const float*)d_in[6];
    float* out = (float*)d_out;

    const int B = in_sizes[0] / 256;  // N_MIC == 1
    const int blocks = (B + 3) / 4;   // 4 elements (waves) per 256-thread block
    pbfd_kernel<<<blocks, 256, 0, stream>>>(mic, lsb, phie, p1, hr, hi, out, B);
}

// Round 4
// 38.010 us; speedup vs baseline: 4.3936x; 1.4644x over previous
//
#include <hip/hip_runtime.h>
#include <math.h>

#define SF 0.99999f
#define PI2 6.283185307179586476925f
#define SWZ(c) ((c) ^ (((c) >> 4) & 15))
// compiler-only fence: orders same-wave LDS write/read phases (HW LDS pipe is
// in-order per wave; this stops compiler reordering).
#define LDSFENCE() asm volatile("" ::: "memory")

template<int SGN>
__device__ __forceinline__ void twmul(float& ur, float& ui, float c, float s) {
    const float ss = (SGN < 0) ? -s : s;
    const float r = ur * c - ui * ss;
    const float i = ui * c + ur * ss;
    ur = r; ui = i;
}

// 8-point DFT across registers. SGN=-1: forward; SGN=+1: inverse.
template<int SGN>
__device__ __forceinline__ void bfly8(float* ur, float* ui) {
    const float C2 = 0.70710678118654752440f;
    float ar[4], ai[4], br[4], bi[4];
#pragma unroll
    for (int m = 0; m < 4; ++m) {
        ar[m] = ur[m] + ur[m + 4]; ai[m] = ui[m] + ui[m + 4];
        br[m] = ur[m] - ur[m + 4]; bi[m] = ui[m] - ui[m + 4];
    }
    float b1r, b1i, b2r, b2i, b3r, b3i;
    if (SGN < 0) {
        b1r = C2 * (br[1] + bi[1]); b1i = C2 * (bi[1] - br[1]);
        b2r = bi[2];                b2i = -br[2];
        b3r = C2 * (bi[3] - br[3]); b3i = -C2 * (br[3] + bi[3]);
    } else {
        b1r = C2 * (br[1] - bi[1]); b1i = C2 * (bi[1] + br[1]);
        b2r = -bi[2];               b2i = br[2];
        b3r = -C2 * (br[3] + bi[3]); b3i = C2 * (br[3] - bi[3]);
    }
    const float e0r = ar[0] + ar[2], e0i = ai[0] + ai[2];
    const float e1r = ar[0] - ar[2], e1i = ai[0] - ai[2];
    const float o0r = ar[1] + ar[3], o0i = ai[1] + ai[3];
    const float o1r = ar[1] - ar[3], o1i = ai[1] - ai[3];
    ur[0] = e0r + o0r; ui[0] = e0i + o0i;
    ur[4] = e0r - o0r; ui[4] = e0i - o0i;
    if (SGN < 0) { ur[2] = e1r + o1i; ui[2] = e1i - o1r; ur[6] = e1r - o1i; ui[6] = e1i + o1r; }
    else         { ur[2] = e1r - o1i; ui[2] = e1i + o1r; ur[6] = e1r + o1i; ui[6] = e1i - o1r; }
    const float f0r = br[0] + b2r, f0i = bi[0] + b2i;
    const float f1r = br[0] - b2r, f1i = bi[0] - b2i;
    const float g0r = b1r + b3r, g0i = b1i + b3i;
    const float g1r = b1r - b3r, g1i = b1i - b3i;
    ur[1] = f0r + g0r; ui[1] = f0i + g0i;
    ur[5] = f0r - g0r; ui[5] = f0i - g0i;
    if (SGN < 0) { ur[3] = f1r + g1i; ui[3] = f1i - g1r; ur[7] = f1r - g1i; ui[7] = f1i + g1r; }
    else         { ur[3] = f1r - g1i; ui[3] = f1i + g1r; ur[7] = f1r + g1i; ui[7] = f1i - g1r; }
}

// Wave-local 512-pt complex FFT, Stockham radix-8, 3 stages, single LDS buffer.
// slot m of lane t <-> element (t + 64*m), natural order both sides. No barriers.
template<int SGN>
__device__ __forceinline__ void fft512w(float* ur, float* ui,
                                        float2* __restrict__ buf,
                                        const float2* __restrict__ tw2,
                                        const float2* __restrict__ tw3,
                                        int t) {
    bfly8<SGN>(ur, ui);
    LDSFENCE();
#pragma unroll
    for (int m = 0; m < 8; ++m) buf[SWZ(8 * t + m)] = make_float2(ur[m], ui[m]);
    LDSFENCE();
#pragma unroll
    for (int m = 0; m < 8; ++m) { const float2 v = buf[SWZ(t + 64 * m)]; ur[m] = v.x; ui[m] = v.y; }
    const int k2 = t & 7;
#pragma unroll
    for (int m = 1; m < 8; ++m) { const float2 w = tw2[m * 8 + k2]; twmul<SGN>(ur[m], ui[m], w.x, w.y); }
    bfly8<SGN>(ur, ui);
    const int jj = ((t >> 3) << 6) + k2;
    LDSFENCE();
#pragma unroll
    for (int m = 0; m < 8; ++m) buf[SWZ(jj + 8 * m)] = make_float2(ur[m], ui[m]);
    LDSFENCE();
#pragma unroll
    for (int m = 0; m < 8; ++m) { const float2 v = buf[SWZ(t + 64 * m)]; ur[m] = v.x; ui[m] = v.y; }
#pragma unroll
    for (int m = 1; m < 8; ++m) { const float2 w = tw3[m * 64 + t]; twmul<SGN>(ur[m], ui[m], w.x, w.y); }
    bfly8<SGN>(ur, ui);
    LDSFENCE();
}

__global__ __launch_bounds__(256, 2) void pbfd_kernel(
    const float* __restrict__ g_mic,   // (B,256)
    const float* __restrict__ g_lsb,   // (B,1280)
    const float* __restrict__ g_phie,  // (B,257)
    const float* __restrict__ g_p1,    // (B,257,4)
    const float* __restrict__ g_hr,    // (B,257,4)
    const float* __restrict__ g_hi,    // (B,257,4)
    float* __restrict__ g_out,         // (B,256)
    int B) {
    __shared__ float2 tw2[64];
    __shared__ float2 tw3[512];
    __shared__ float2 xch[4][512];     // one exchange buffer per wave

    const int tid = threadIdx.x;
    for (int e = tid; e < 512; e += 256) {
        const int m = e >> 6, tt = e & 63;
        float s, c;
        sincosf(PI2 * (float)(m * tt) * (1.0f / 512.0f), &s, &c);
        tw3[e] = make_float2(c, s);
    }
    if (tid < 64) {
        const int m = tid >> 3, k = tid & 7;
        float s, c;
        sincosf(PI2 * (float)(m * k) * (1.0f / 64.0f), &s, &c);
        tw2[tid] = make_float2(c, s);
    }
    __syncthreads();  // the only barrier

    const int w = tid >> 6;
    const int t = tid & 63;
    const int elem = blockIdx.x * 4 + w;
    if (elem >= B) return;
    float2* buf = &xch[w][0];
    const int ml = (64 - t) & 63;  // mirror lane: bin 512-k lives at (ml, 7-m) for t>=1

    float mv[4];
    {
        const float* mp = g_mic + (size_t)elem * 256;
#pragma unroll
        for (int q = 0; q < 4; ++q) mv[q] = mp[t + 64 * q];
    }

    // ---- X: 4 real frame-FFTs as 2 paired complex FFTs; keep low bins + lane0 Nyquist ----
    float xr[4][4], xi[4][4], xn[4];
    {
        const float* lb = g_lsb + (size_t)elem * 1280;
#pragma unroll
        for (int pr = 0; pr < 2; ++pr) {
            float ur[8], ui[8];
#pragma unroll
            for (int m = 0; m < 8; ++m) {
                ur[m] = lb[(2 * pr) * 256 + t + 64 * m];
                ui[m] = lb[(2 * pr + 1) * 256 + t + 64 * m];
            }
            fft512w<-1>(ur, ui, buf, tw2, tw3, t);
#pragma unroll
            for (int m = 0; m < 4; ++m) {
                float zmr = __shfl(ur[7 - m], ml);
                float zmi = __shfl(ui[7 - m], ml);
                if (t == 0) {  // lane0: mirror of bin 64m is slot 8-m (self for m=0)
                    zmr = (m == 0) ? ur[0] : ur[8 - m];
                    zmi = (m == 0) ? ui[0] : ui[8 - m];
                }
                xr[2 * pr][m]     = 0.5f * (ur[m] + zmr);
                xi[2 * pr][m]     = 0.5f * (ui[m] - zmi);
                xr[2 * pr + 1][m] = 0.5f * (ui[m] + zmi);
                xi[2 * pr + 1][m] = -0.5f * (ur[m] - zmr);
            }
            if (t == 0) { xn[2 * pr] = ur[4]; xn[2 * pr + 1] = ui[4]; }  // X[256] real / imag-packed
        }
    }

    // ---- H (low bins; lane0: real part of H[256] — its imag is dead for the output) ----
    float hr_[4][4], hi_[4][4], hn[4];
    {
        const float4* hr4 = (const float4*)g_hr + (size_t)elem * 257;
        const float4* hi4 = (const float4*)g_hi + (size_t)elem * 257;
#pragma unroll
        for (int m = 0; m < 4; ++m) {
            const float4 a = hr4[t + 64 * m], b = hi4[t + 64 * m];
            hr_[0][m] = a.x; hr_[1][m] = a.y; hr_[2][m] = a.z; hr_[3][m] = a.w;
            hi_[0][m] = b.x; hi_[1][m] = b.y; hi_[2][m] = b.z; hi_[3][m] = b.w;
        }
    }
    float pn[4] = {0, 0, 0, 0};
    if (t == 0) {
        const float4* hr4 = (const float4*)g_hr + (size_t)elem * 257;
        const float4* p14 = (const float4*)g_p1 + (size_t)elem * 257;
        const float4 a = hr4[256], p = p14[256];
        hn[0] = a.x; hn[1] = a.y; hn[2] = a.z; hn[3] = a.w;
        pn[0] = p.x; pn[1] = p.y; pn[2] = p.z; pn[3] = p.w;
    }

    // C = sum_j X*H at low slots; Hermitian high-half reconstruction; IFFT; o4 = Re(out)[4..7]/512
    auto sum_ifft = [&](float o4[4]) {
        float ur[8], ui[8];
#pragma unroll
        for (int m = 0; m < 4; ++m) {
            float cr = 0.f, ci = 0.f;
#pragma unroll
            for (int j = 0; j < 4; ++j) {
                cr += xr[j][m] * hr_[j][m] - xi[j][m] * hi_[j][m];
                ci += xr[j][m] * hi_[j][m] + xi[j][m] * hr_[j][m];
            }
            ur[m] = cr; ui[m] = ci;
        }
#pragma unroll
        for (int m = 4; m < 8; ++m) {  // high slot = conj(mirror-lane low slot 7-m)
            const float cr = __shfl(ur[7 - m], ml);
            const float ci = __shfl(ui[7 - m], ml);
            ur[m] = cr; ui[m] = -ci;
        }
        if (t == 0) {
            ur[5] = ur[3]; ui[5] = -ui[3];
            ur[6] = ur[2]; ui[6] = -ui[2];
            ur[7] = ur[1]; ui[7] = -ui[1];
            float cn = 0.f;
#pragma unroll
            for (int j = 0; j < 4; ++j) cn += xn[j] * hn[j];
            ur[4] = cn; ui[4] = 0.f;  // Nyquist: real
        }
        fft512w<1>(ur, ui, buf, tw2, tw3, t);
#pragma unroll
        for (int q = 0; q < 4; ++q) o4[q] = ur[4 + q] * (1.0f / 512.0f);
    };

    // ---- est (H prior), d = mic - est ----
    float d4[4];
    {
        float o4[4];
        sum_ifft(o4);
#pragma unroll
        for (int q = 0; q < 4; ++q) d4[q] = mv[q] - o4[q];
    }

    // ---- E = FFT([zeros(256); d]) ----
    float er[4], ei[4], en = 0.f;
    {
        float ur[8], ui[8];
#pragma unroll
        for (int m = 0; m < 4; ++m) { ur[m] = 0.f; ui[m] = 0.f; }
#pragma unroll
        for (int q = 0; q < 4; ++q) { ur[4 + q] = d4[q]; ui[4 + q] = 0.f; }
        fft512w<-1>(ur, ui, buf, tw2, tw3, t);
#pragma unroll
        for (int m = 0; m < 4; ++m) { er[m] = ur[m]; ei[m] = ui[m]; }
        if (t == 0) en = ur[4];
    }

    // ---- phi_e ----
    float pe[4], pen = 0.f;
    {
        const float* php = g_phie + (size_t)elem * 257;
#pragma unroll
        for (int m = 0; m < 4; ++m)
            pe[m] = 0.7f * php[t + 64 * m] + 0.3f * (er[m] * er[m] + ei[m] * ei[m]);
        if (t == 0) pen = 0.7f * php[256] + 0.3f * en * en;
    }

    // ---- gradient: partitions paired (0,1), (2,3): IFFT(KE0 + i*KE1) -> mask -> FFT -> unpack ----
    {
        const float4* p14 = (const float4*)g_p1 + (size_t)elem * 257;
#pragma unroll
        for (int pr = 0; pr < 2; ++pr) {
            const int j0 = 2 * pr, j1 = 2 * pr + 1;
            float ur[8], ui[8], gr[4], gi[4];
#pragma unroll
            for (int m = 0; m < 4; ++m) {
                // KE_j = P1_j * conj(X_j) / R_j * E  (P1 reloaded here, L1/L2-hot)
                const float4 p = p14[t + 64 * m];
                const float pa = pr ? p.z : p.x;
                const float pb = pr ? p.w : p.y;
                const float xxa = xr[j0][m] * xr[j0][m] + xi[j0][m] * xi[j0][m];
                const float Ra = xxa * pa + 2.f * pe[m] + 1e-10f;
                const float ia = 1.f / Ra;
                const float kra = pa * xr[j0][m] * ia, kia = -pa * xi[j0][m] * ia;
                const float a_r = kra * er[m] - kia * ei[m];
                const float a_i = kra * ei[m] + kia * er[m];
                const float xxb = xr[j1][m] * xr[j1][m] + xi[j1][m] * xi[j1][m];
                const float Rb = xxb * pb + 2.f * pe[m] + 1e-10f;
                const float ib = 1.f / Rb;
                const float krb = pb * xr[j1][m] * ib, kib = -pb * xi[j1][m] * ib;
                const float b_r = krb * er[m] - kib * ei[m];
                const float b_i = krb * ei[m] + kib * er[m];
                ur[m] = a_r - b_i;  ui[m] = a_i + b_r;   // KE0 + i*KE1
                gr[m] = a_r + b_i;  gi[m] = b_r - a_i;   // conj(KE0) + i*conj(KE1) (export for mirror)
            }
#pragma unroll
            for (int m = 4; m < 8; ++m) {
                ur[m] = __shfl(gr[7 - m], ml);
                ui[m] = __shfl(gi[7 - m], ml);
            }
            if (t == 0) {
                ur[5] = gr[3]; ui[5] = gi[3];
                ur[6] = gr[2]; ui[6] = gi[2];
                ur[7] = gr[1]; ui[7] = gi[1];
                const float Rn0 = xn[j0] * xn[j0] * pn[j0] + 2.f * pen + 1e-10f;
                const float Rn1 = xn[j1] * xn[j1] * pn[j1] + 2.f * pen + 1e-10f;
                ur[4] = pn[j0] * xn[j0] / Rn0 * en;   // KE0[256] (real)
                ui[4] = pn[j1] * xn[j1] / Rn1 * en;   // KE1[256] (real)
            }
            fft512w<1>(ur, ui, buf, tw2, tw3, t);  // -> 512*(dH0 + i*dH1), natural order
            // mask n<256 (slots m<4), scale 1/512, FFT the still-packed pair
#pragma unroll
            for (int m = 0; m < 4; ++m) { ur[m] *= (1.0f / 512.0f); ui[m] *= (1.0f / 512.0f); }
#pragma unroll
            for (int m = 4; m < 8; ++m) { ur[m] = 0.f; ui[m] = 0.f; }
            fft512w<-1>(ur, ui, buf, tw2, tw3, t);  // Z = fd_dH0 + i*fd_dH1
            // unpack at low slots: fd0 = (Z + conj(Zm))/2, fd1 = -i/2 (Z - conj(Zm))
#pragma unroll
            for (int m = 0; m < 4; ++m) {
                float zmr = __shfl(ur[7 - m], ml);
                float zmi = __shfl(ui[7 - m], ml);
                if (t == 0) {
                    zmr = (m == 0) ? ur[0] : ur[8 - m];
                    zmi = (m == 0) ? ui[0] : ui[8 - m];
                }
                const float f0r = 0.5f * (ur[m] + zmr), f0i = 0.5f * (ui[m] - zmi);
                const float f1r = 0.5f * (ui[m] + zmi), f1i = -0.5f * (ur[m] - zmr);
                hr_[j0][m] = SF * (hr_[j0][m] + f0r);
                hi_[j0][m] = SF * (hi_[j0][m] + f0i);
                hr_[j1][m] = SF * (hr_[j1][m] + f1r);
                hi_[j1][m] = SF * (hi_[j1][m] + f1i);
            }
            if (t == 0) {
                hn[j0] = SF * (hn[j0] + ur[4]);  // fd_dH0[256] = Re(Z4)
                hn[j1] = SF * (hn[j1] + ui[4]);  // fd_dH1[256] = Im(Z4)
            }
        }
    }

    // ---- enhanced = mic - Re(IFFT(sum X*H_new))[256:] ----
    {
        float o4[4];
        sum_ifft(o4);
        float* op = g_out + (size_t)elem * 256;
#pragma unroll
        for (int q = 0; q < 4; ++q) op[t + 64 * q] = mv[q] - o4[q];
    }
}

extern "C" void kernel_launch(void* const* d_in, const int* in_sizes, int n_in,
                              void* d_out, int out_size, void* d_ws, size_t ws_size,
                              hipStream_t stream) {
    const float* mic  = (const float*)d_in[0];
    const float* lsb  = (const float*)d_in[1];
    const float* phie = (const float*)d_in[2];
    // d_in[3] = phi_f: dead for the 'enhanced' output
    const float* p1   = (const float*)d_in[4];
    const float* hr   = (const float*)d_in[5];
    const float* hi   = (const float*)d_in[6];
    float* out = (float*)d_out;

    const int B = in_sizes[0] / 256;  // N_MIC == 1
    const int blocks = (B + 3) / 4;   // 4 elements (waves) per 256-thread block
    pbfd_kernel<<<blocks, 256, 0, stream>>>(mic, lsb, phie, p1, hr, hi, out, B);
}